// Round 5
// baseline (280.298 us; speedup 1.0000x reference)
//
#include <hip/hip_runtime.h>

// SDPA B=2,H=16,S=2048,DK=DV=64 fp32, additive mask (1,1,S,S).
// Two-kernel design:
//  1) prepass: convert Q(,pre-scaled)/K/V to bf16 fragment-major layout in d_ws
//     (per 32-row block, per 16-k chunk: 64 lanes x 16B contiguous).
//  2) main: barrier-free flash attention, 32x32x16 MFMA, all operands via
//     coalesced b128 global loads (L2-resident), in-register softmax,
//     in-block split-K x4 (4 waves = 4 kv quarters), LDS only for the merge.

constexpr int Sn = 2048, Dn = 64, NHEAD = 32;   // 32 = B*H
constexpr float LOG2E = 1.44269504088896f;
constexpr float QSCALE = 0.125f * LOG2E;        // 1/sqrt(64) * log2(e)
constexpr float DEFER_THR = 8.0f;               // log2 units
constexpr size_t FRAG_HEAD = 64 * 4 * 512;      // elems per head per tensor (131072)

typedef __attribute__((ext_vector_type(8))) short bf16x8;
typedef __attribute__((ext_vector_type(4))) float f32x4;
typedef __attribute__((ext_vector_type(16))) float f32x16;

union FragU { bf16x8 v; unsigned u[4]; unsigned short s[8]; };

__device__ __forceinline__ unsigned cvt_pk(float lo, float hi) {
  unsigned r;
  asm("v_cvt_pk_bf16_f32 %0, %1, %2" : "=v"(r) : "v"(lo), "v"(hi));
  return r;
}
__device__ __forceinline__ float exp2_fast(float x) {
  float r;
  asm("v_exp_f32 %0, %1" : "=v"(r) : "v"(x));
  return r;
}

// ---------------- prepass: fp32 -> bf16 fragment-major ----------------
// grid: 32 heads x 64 blk32 = 2048 blocks, 256 threads (4 waves).
// wave w handles chunk w of K (kc=w), Q (kc=w), V (g=w: c=g>>1, dt=g&1).
__global__ __launch_bounds__(256) void sdpa_prep(
    const float* __restrict__ Q, const float* __restrict__ K,
    const float* __restrict__ V, unsigned short* __restrict__ Qb,
    unsigned short* __restrict__ Kb, unsigned short* __restrict__ Vb) {
  const int tid = threadIdx.x, lane = tid & 63, w = tid >> 6;
  const int l31 = lane & 31, hi = lane >> 5;
  const int bid = blockIdx.x;
  const int head = bid >> 6, blk = bid & 63;
  const size_t hoff = (size_t)head * Sn * Dn;
  const size_t foff = ((size_t)(head * 64 + blk) * 4 + w) * 512 + (size_t)lane * 8;

  {  // K fragment: lane l -> K[blk*32+l31][16w+8hi .. +7]
    const float* p = K + hoff + (size_t)(blk * 32 + l31) * Dn + 16 * w + 8 * hi;
    f32x4 a = *(const f32x4*)p, b = *(const f32x4*)(p + 4);
    FragU f;
    f.u[0] = cvt_pk(a[0], a[1]); f.u[1] = cvt_pk(a[2], a[3]);
    f.u[2] = cvt_pk(b[0], b[1]); f.u[3] = cvt_pk(b[2], b[3]);
    *(bf16x8*)&Kb[foff] = f.v;
  }
  {  // Q fragment (pre-scaled): qtile = blk
    const float* p = Q + hoff + (size_t)(blk * 32 + l31) * Dn + 16 * w + 8 * hi;
    f32x4 a = *(const f32x4*)p, b = *(const f32x4*)(p + 4);
    FragU f;
    f.u[0] = cvt_pk(a[0] * QSCALE, a[1] * QSCALE);
    f.u[1] = cvt_pk(a[2] * QSCALE, a[3] * QSCALE);
    f.u[2] = cvt_pk(b[0] * QSCALE, b[1] * QSCALE);
    f.u[3] = cvt_pk(b[2] * QSCALE, b[3] * QSCALE);
    *(bf16x8*)&Qb[foff] = f.v;
  }
  {  // V^T fragment: g=w, c=w>>1, dt=w&1; lane l -> V[blk*32+16c+8hi+j][dt*32+l31]
    const int c = w >> 1, dt = w & 1;
    const float* p = V + hoff + (size_t)(blk * 32 + 16 * c + 8 * hi) * Dn + dt * 32 + l31;
    float vv[8];
#pragma unroll
    for (int j = 0; j < 8; ++j) vv[j] = p[(size_t)j * Dn];
    FragU f;
    f.u[0] = cvt_pk(vv[0], vv[1]); f.u[1] = cvt_pk(vv[2], vv[3]);
    f.u[2] = cvt_pk(vv[4], vv[5]); f.u[3] = cvt_pk(vv[6], vv[7]);
    *(bf16x8*)&Vb[foff] = f.v;
  }
}

// ---------------- main: barrier-free FA + split-K x4 merge ----------------
// grid: 32 heads x 64 qtiles = 2048 blocks, 256 threads (4 waves = 4 kv quarters).
__global__ __launch_bounds__(256, 6) void sdpa_fa5(
    const unsigned short* __restrict__ Qb, const unsigned short* __restrict__ Kb,
    const unsigned short* __restrict__ Vb, const float* __restrict__ M,
    float* __restrict__ Out) {
  __shared__ __align__(16) float OmS[2][32][68];  // 2 slots, stride 68 (conflict-tamed)
  __shared__ float mlS[2][32][2];

  const int tid = threadIdx.x;
  const int lane = tid & 63;
  const int wave = tid >> 6;   // kv quarter 0..3
  const int l31 = lane & 31;
  const int hi = lane >> 5;

  int bid = blockIdx.x;
  bid = (bid & 7) * ((int)gridDim.x >> 3) + (bid >> 3);  // XCD chunk swizzle (2048%8==0)
  const int head = bid >> 6;
  const int qblk = bid & 63;   // 32-row q tile

  const unsigned short* __restrict__ Qh = Qb + ((size_t)(head * 64 + qblk) * 4) * 512;
  const unsigned short* __restrict__ Kh = Kb + (size_t)head * FRAG_HEAD;
  const unsigned short* __restrict__ Vh = Vb + (size_t)head * FRAG_HEAD;
  const float* __restrict__ Mq =
      M + (size_t)(qblk * 32 + l31) * Sn + wave * 512 + 4 * hi;
  float* __restrict__ Oh = Out + (size_t)head * Sn * Dn;

  // Q fragments: 4 coalesced b128 loads
  FragU qf[4];
#pragma unroll
  for (int kc = 0; kc < 4; ++kc)
    qf[kc].v = *(const bf16x8*)&Qh[kc * 512 + lane * 8];

  f32x16 acc0, acc1;
#pragma unroll
  for (int i = 0; i < 16; ++i) { acc0[i] = 0.f; acc1[i] = 0.f; }
  float m_run = -1e30f, l_run = 0.f;

  for (int it = 0; it < 16; ++it) {
    const int blk = wave * 16 + it;  // kv block of 32
    const unsigned short* kbase = Kh + (size_t)blk * 2048;
    const unsigned short* vbase = Vh + (size_t)blk * 2048;

    // ---- QK^T: S^T [kv 32][q 32] ----
    f32x16 st;
#pragma unroll
    for (int i = 0; i < 16; ++i) st[i] = 0.f;
    __builtin_amdgcn_s_setprio(1);
#pragma unroll
    for (int kc = 0; kc < 4; ++kc) {
      FragU kf;
      kf.v = *(const bf16x8*)&kbase[kc * 512 + lane * 8];
      st = __builtin_amdgcn_mfma_f32_32x32x16_bf16(kf.v, qf[kc].v, st, 0, 0, 0);
    }
    __builtin_amdgcn_s_setprio(0);

    // ---- mask (f32 gather; lines fully consumed across lanes) ----
    f32x4 mk[4];
#pragma unroll
    for (int m = 0; m < 4; ++m) mk[m] = *(const f32x4*)(Mq + it * 32 + 8 * m);

    float p[16];
#pragma unroll
    for (int m = 0; m < 4; ++m)
#pragma unroll
      for (int e = 0; e < 4; ++e)
        p[4 * m + e] = fmaf(mk[m][e], LOG2E, st[4 * m + e]);

    // ---- row max: in-lane tree + partner half ----
    float t8[8];
#pragma unroll
    for (int i = 0; i < 8; ++i) t8[i] = fmaxf(p[2 * i], p[2 * i + 1]);
    float t4a = fmaxf(t8[0], t8[1]), t4b = fmaxf(t8[2], t8[3]);
    float t4c = fmaxf(t8[4], t8[5]), t4d = fmaxf(t8[6], t8[7]);
    float mx = fmaxf(fmaxf(t4a, t4b), fmaxf(t4c, t4d));
    mx = fmaxf(mx, __shfl_xor(mx, 32, 64));

    // T13 defer-max
    if (!__all(mx <= m_run + DEFER_THR)) {
      const float mn = fmaxf(m_run, mx);
      const float corr = exp2_fast(m_run - mn);
      m_run = mn;
      l_run *= corr;
#pragma unroll
      for (int i = 0; i < 16; ++i) { acc0[i] *= corr; acc1[i] *= corr; }
    }

    float ps = 0.f;
#pragma unroll
    for (int i = 0; i < 16; ++i) {
      p[i] = exp2_fast(p[i] - m_run);
      ps += p[i];
    }
    ps += __shfl_xor(ps, 32, 64);
    l_run += ps;

    // ---- pack P, build P^T B-fragments via partner exchange ----
    unsigned W[4][2];
#pragma unroll
    for (int m = 0; m < 4; ++m)
#pragma unroll
      for (int s = 0; s < 2; ++s)
        W[m][s] = cvt_pk(p[4 * m + 2 * s], p[4 * m + 2 * s + 1]);

    FragU pf[2];
#pragma unroll
    for (int cc = 0; cc < 2; ++cc)
#pragma unroll
      for (int s = 0; s < 2; ++s) {
        const unsigned a = W[2 * cc][s];
        const unsigned b = W[2 * cc + 1][s];
        const unsigned pa = (unsigned)__shfl_xor((int)a, 32, 64);
        const unsigned pb = (unsigned)__shfl_xor((int)b, 32, 64);
        pf[cc].u[s] = hi ? pb : a;
        pf[cc].u[2 + s] = hi ? b : pa;
      }

    // ---- PV: O^T += V^T . P^T ----
    __builtin_amdgcn_s_setprio(1);
#pragma unroll
    for (int c = 0; c < 2; ++c) {
      FragU vf0, vf1;
      vf0.v = *(const bf16x8*)&vbase[(c * 2 + 0) * 512 + lane * 8];
      vf1.v = *(const bf16x8*)&vbase[(c * 2 + 1) * 512 + lane * 8];
      acc0 = __builtin_amdgcn_mfma_f32_32x32x16_bf16(vf0.v, pf[c].v, acc0, 0, 0, 0);
      acc1 = __builtin_amdgcn_mfma_f32_32x32x16_bf16(vf1.v, pf[c].v, acc1, 0, 0, 0);
    }
    __builtin_amdgcn_s_setprio(0);
  }

  // ---- split-K x4 merge (all 4 waves hold the SAME 32 q rows) ----
  // Stage A: waves 1,3 publish partials.
  if (wave & 1) {
    const int s = wave >> 1;
    float* base = &OmS[s][l31][0];
#pragma unroll
    for (int m = 0; m < 4; ++m) {
      f32x4 a, b;
#pragma unroll
      for (int e = 0; e < 4; ++e) { a[e] = acc0[4 * m + e]; b[e] = acc1[4 * m + e]; }
      *(f32x4*)(base + 8 * m + 4 * hi) = a;
      *(f32x4*)(base + 32 + 8 * m + 4 * hi) = b;
    }
    if (!hi) { mlS[s][l31][0] = m_run; mlS[s][l31][1] = l_run; }
  }
  __syncthreads();
  // Stage B: wave0 merges slot0; wave2 merges slot1 and publishes back.
  if (!(wave & 1)) {
    const int s = wave >> 1;
    const float m2 = mlS[s][l31][0];
    const float l2 = mlS[s][l31][1];
    const float mm = fmaxf(m_run, m2);
    const float e1 = exp2_fast(m_run - mm);
    const float e2 = exp2_fast(m2 - mm);
    m_run = mm;
    l_run = l_run * e1 + l2 * e2;
    float* base = &OmS[s][l31][0];
#pragma unroll
    for (int m = 0; m < 4; ++m) {
      f32x4 o2a = *(const f32x4*)(base + 8 * m + 4 * hi);
      f32x4 o2b = *(const f32x4*)(base + 32 + 8 * m + 4 * hi);
#pragma unroll
      for (int e = 0; e < 4; ++e) {
        acc0[4 * m + e] = acc0[4 * m + e] * e1 + o2a[e] * e2;
        acc1[4 * m + e] = acc1[4 * m + e] * e1 + o2b[e] * e2;
      }
    }
    if (wave == 2) {  // publish merged {2,3}
#pragma unroll
      for (int m = 0; m < 4; ++m) {
        f32x4 a, b;
#pragma unroll
        for (int e = 0; e < 4; ++e) { a[e] = acc0[4 * m + e]; b[e] = acc1[4 * m + e]; }
        *(f32x4*)(base + 8 * m + 4 * hi) = a;
        *(f32x4*)(base + 32 + 8 * m + 4 * hi) = b;
      }
      if (!hi) { mlS[1][l31][0] = m_run; mlS[1][l31][1] = l_run; }
    }
  }
  __syncthreads();
  // Stage C: wave0 final-merges slot1 and writes output.
  if (wave == 0) {
    const float m2 = mlS[1][l31][0];
    const float l2 = mlS[1][l31][1];
    const float mm = fmaxf(m_run, m2);
    const float e1 = exp2_fast(m_run - mm);
    const float e2 = exp2_fast(m2 - mm);
    const float inv = 1.0f / (l_run * e1 + l2 * e2);
    const float* base = &OmS[1][l31][0];
    const int qrow = qblk * 32 + l31;
#pragma unroll
    for (int m = 0; m < 4; ++m) {
      f32x4 o2a = *(const f32x4*)(base + 8 * m + 4 * hi);
      f32x4 o2b = *(const f32x4*)(base + 32 + 8 * m + 4 * hi);
      f32x4 oa, ob;
#pragma unroll
      for (int e = 0; e < 4; ++e) {
        oa[e] = (acc0[4 * m + e] * e1 + o2a[e] * e2) * inv;
        ob[e] = (acc1[4 * m + e] * e1 + o2b[e] * e2) * inv;
      }
      *(f32x4*)&Oh[(size_t)qrow * Dn + 8 * m + 4 * hi] = oa;
      *(f32x4*)&Oh[(size_t)qrow * Dn + 32 + 8 * m + 4 * hi] = ob;
    }
  }
}

extern "C" void kernel_launch(void* const* d_in, const int* in_sizes, int n_in,
                              void* d_out, int out_size, void* d_ws, size_t ws_size,
                              hipStream_t stream) {
  const float* Q = (const float*)d_in[0];
  const float* K = (const float*)d_in[1];
  const float* V = (const float*)d_in[2];
  const float* M = (const float*)d_in[3];
  float* O = (float*)d_out;

  unsigned short* Qb = (unsigned short*)d_ws;                       // 8 MB
  unsigned short* Kb = Qb + (size_t)NHEAD * FRAG_HEAD;              // 8 MB
  unsigned short* Vb = Kb + (size_t)NHEAD * FRAG_HEAD;              // 8 MB

  sdpa_prep<<<dim3(NHEAD * 64), dim3(256), 0, stream>>>(Q, K, V, Qb, Kb, Vb);
  sdpa_fa5<<<dim3(NHEAD * 64), dim3(256), 0, stream>>>(Qb, Kb, Vb, M, O);
}

// Round 6
// 189.398 us; speedup vs baseline: 1.4799x; 1.4799x over previous
//
#include <hip/hip_runtime.h>

// SDPA B=2,H=16,S=2048,DK=DV=64 fp32, additive mask (1,1,S,S).
// Two-kernel design, v2:
//  prepass: Q(prescaled)/K/V^T -> bf16 fragment-major in d_ws (V via LDS
//           transpose); mask -> bf16*LOG2E in MFMA-fragment order
//           [qblk][kvb][lane][16] so main reads it fully coalesced.
//  main: barrier-free FA, 32x32x16 MFMA, in-register softmax, split-K x4
//        across waves, LDS only for the 3-stage merge. Head-pinned XCD
//        mapping keeps K/V frags (2MB) L2-resident per XCD and gives
//        mask-frag slices 4-way concurrent reuse.

constexpr int Sn = 2048, Dn = 64, NHEAD = 32;   // NHEAD = B*H
constexpr float LOG2E = 1.44269504088896f;
constexpr float QSCALE = 0.125f * LOG2E;        // 1/sqrt(64) * log2(e)
constexpr float DEFER_THR = 8.0f;               // log2 units
constexpr size_t FRAG_HEAD = 64 * 4 * 512;      // 131072 elems/head (Q,K,V frag)

typedef __attribute__((ext_vector_type(8))) short bf16x8;
typedef __attribute__((ext_vector_type(4))) float f32x4;
typedef __attribute__((ext_vector_type(16))) float f32x16;

union FragU { bf16x8 v; unsigned u[4]; unsigned short s[8]; };

__device__ __forceinline__ unsigned cvt_pk(float lo, float hi) {
  unsigned r;
  asm("v_cvt_pk_bf16_f32 %0, %1, %2" : "=v"(r) : "v"(lo), "v"(hi));
  return r;
}
__device__ __forceinline__ float exp2_fast(float x) {
  float r;
  asm("v_exp_f32 %0, %1" : "=v"(r) : "v"(x));
  return r;
}
__device__ __forceinline__ float bf2f(unsigned short b) {
  union { unsigned u; float f; } c;
  c.u = ((unsigned)b) << 16;
  return c.f;
}

// ---------------- prepass ----------------
// grid: 32 heads x 64 blk32 = 2048 blocks, 256 threads.
__global__ __launch_bounds__(256) void sdpa_prep6(
    const float* __restrict__ Q, const float* __restrict__ K,
    const float* __restrict__ V, const float* __restrict__ M,
    unsigned short* __restrict__ Qb, unsigned short* __restrict__ Kb,
    unsigned short* __restrict__ Vb, unsigned short* __restrict__ Mf) {
  __shared__ unsigned short Vl[32][64];  // bf16 V tile for transpose

  const int tid = threadIdx.x, lane = tid & 63, w = tid >> 6;
  const int l31 = lane & 31, hi = lane >> 5;
  const int bid = blockIdx.x;
  const int head = bid >> 6, blk = bid & 63;
  const size_t hoff = (size_t)head * Sn * Dn;
  const size_t foff = ((size_t)(head * 64 + blk) * 4 + w) * 512 + (size_t)lane * 8;

  // ---- V: coalesced load -> bf16 LDS ----
  {
    const int vrow = tid >> 3, vc8 = (tid & 7) * 8;
    const float* vp = V + hoff + (size_t)(blk * 32 + vrow) * Dn + vc8;
    f32x4 a = *(const f32x4*)vp, b = *(const f32x4*)(vp + 4);
    FragU f;
    f.u[0] = cvt_pk(a[0], a[1]); f.u[1] = cvt_pk(a[2], a[3]);
    f.u[2] = cvt_pk(b[0], b[1]); f.u[3] = cvt_pk(b[2], b[3]);
    *(bf16x8*)&Vl[vrow][vc8] = f.v;
  }

  // ---- K fragment: lane l -> K[blk*32+l31][16w+8hi .. +7] ----
  {
    const float* p = K + hoff + (size_t)(blk * 32 + l31) * Dn + 16 * w + 8 * hi;
    f32x4 a = *(const f32x4*)p, b = *(const f32x4*)(p + 4);
    FragU f;
    f.u[0] = cvt_pk(a[0], a[1]); f.u[1] = cvt_pk(a[2], a[3]);
    f.u[2] = cvt_pk(b[0], b[1]); f.u[3] = cvt_pk(b[2], b[3]);
    *(bf16x8*)&Kb[foff] = f.v;
  }
  // ---- Q fragment, pre-scaled ----
  {
    const float* p = Q + hoff + (size_t)(blk * 32 + l31) * Dn + 16 * w + 8 * hi;
    f32x4 a = *(const f32x4*)p, b = *(const f32x4*)(p + 4);
    FragU f;
    f.u[0] = cvt_pk(a[0] * QSCALE, a[1] * QSCALE);
    f.u[1] = cvt_pk(a[2] * QSCALE, a[3] * QSCALE);
    f.u[2] = cvt_pk(b[0] * QSCALE, b[1] * QSCALE);
    f.u[3] = cvt_pk(b[2] * QSCALE, b[3] * QSCALE);
    *(bf16x8*)&Qb[foff] = f.v;
  }
  // ---- mask fragment (x LOG2E): dest [qblk][kvb][lane][16] ----
  // this block handles lane-blocks lb = bid*128 + (tid>>1), half h = tid&1
  {
    const int lb = bid * 128 + (tid >> 1);
    const int h = tid & 1;
    const int qmb = lb >> 12, kvb = (lb >> 6) & 63, mlane = lb & 63;
    const int ml31 = mlane & 31, mhi = mlane >> 5;
    const float* mp = M + (size_t)(qmb * 32 + ml31) * Sn + kvb * 32 + 4 * mhi + 16 * h;
    f32x4 x0 = *(const f32x4*)mp;         // m = 2h,   e 0..3 (kv 8m+4hi+e)
    f32x4 x1 = *(const f32x4*)(mp + 8);   // m = 2h+1, e 0..3
    FragU g;
    g.u[0] = cvt_pk(x0[0] * LOG2E, x0[1] * LOG2E);
    g.u[1] = cvt_pk(x0[2] * LOG2E, x0[3] * LOG2E);
    g.u[2] = cvt_pk(x1[0] * LOG2E, x1[1] * LOG2E);
    g.u[3] = cvt_pk(x1[2] * LOG2E, x1[3] * LOG2E);
    *(bf16x8*)&Mf[(size_t)lb * 16 + h * 8] = g.v;
  }

  __syncthreads();
  // ---- V^T fragment from LDS: w -> (c=w>>1, dt=w&1);
  // lane l elem j = V[blk*32+16c+8hi+j][dt*32+l31] ----
  {
    const int c = w >> 1, dt = w & 1;
    FragU f;
#pragma unroll
    for (int j = 0; j < 8; ++j) f.s[j] = Vl[16 * c + 8 * hi + j][dt * 32 + l31];
    *(bf16x8*)&Vb[foff] = f.v;
  }
}

// ---------------- main: barrier-free FA + split-K x4 merge ----------------
// grid: 2048 blocks, 256 threads (4 waves = 4 kv quarters).
// Head-pinned XCD mapping (assumes XCD = blockIdx % 8):
//   x = bid&7 -> heads 4x..4x+3 ; t = bid>>3: head = 4x+(t&3), qblk = t>>2.
__global__ __launch_bounds__(256, 6) void sdpa_fa6(
    const unsigned short* __restrict__ Qb, const unsigned short* __restrict__ Kb,
    const unsigned short* __restrict__ Vb, const unsigned short* __restrict__ Mf,
    float* __restrict__ Out) {
  __shared__ __align__(16) float OmS[2][32][68];
  __shared__ float mlS[2][32][2];

  const int tid = threadIdx.x;
  const int lane = tid & 63;
  const int wave = tid >> 6;   // kv quarter 0..3
  const int l31 = lane & 31;
  const int hi = lane >> 5;

  const int x = blockIdx.x & 7;
  const int t = blockIdx.x >> 3;
  const int head = 4 * x + (t & 3);
  const int qblk = t >> 2;

  const unsigned short* __restrict__ Qh = Qb + ((size_t)(head * 64 + qblk) * 4) * 512;
  const unsigned short* __restrict__ Kh = Kb + (size_t)head * FRAG_HEAD;
  const unsigned short* __restrict__ Vh = Vb + (size_t)head * FRAG_HEAD;
  const unsigned short* __restrict__ Mq = Mf + (size_t)qblk * 65536 + (size_t)lane * 16;
  float* __restrict__ Oh = Out + (size_t)head * Sn * Dn;

  FragU qf[4];
#pragma unroll
  for (int kc = 0; kc < 4; ++kc)
    qf[kc].v = *(const bf16x8*)&Qh[kc * 512 + lane * 8];

  f32x16 acc0, acc1;
#pragma unroll
  for (int i = 0; i < 16; ++i) { acc0[i] = 0.f; acc1[i] = 0.f; }
  float m_run = -1e30f, l_run = 0.f;

  for (int it = 0; it < 16; ++it) {
    const int blk = wave * 16 + it;  // kv block of 32
    const unsigned short* kbase = Kh + (size_t)blk * 2048;
    const unsigned short* vbase = Vh + (size_t)blk * 2048;

    // ---- QK^T ----
    f32x16 st;
#pragma unroll
    for (int i = 0; i < 16; ++i) st[i] = 0.f;
    __builtin_amdgcn_s_setprio(1);
#pragma unroll
    for (int kc = 0; kc < 4; ++kc) {
      FragU kf;
      kf.v = *(const bf16x8*)&kbase[kc * 512 + lane * 8];
      st = __builtin_amdgcn_mfma_f32_32x32x16_bf16(kf.v, qf[kc].v, st, 0, 0, 0);
    }
    __builtin_amdgcn_s_setprio(0);

    // ---- mask: two coalesced b128 loads, already *LOG2E, bf16 ----
    FragU m0, m1;
    m0.v = *(const bf16x8*)&Mq[(size_t)blk * 1024];
    m1.v = *(const bf16x8*)&Mq[(size_t)blk * 1024 + 8];

    float p[16];
#pragma unroll
    for (int i = 0; i < 8; ++i) p[i] = st[i] + bf2f(m0.s[i]);
#pragma unroll
    for (int i = 8; i < 16; ++i) p[i] = st[i] + bf2f(m1.s[i - 8]);

    // ---- row max ----
    float t8[8];
#pragma unroll
    for (int i = 0; i < 8; ++i) t8[i] = fmaxf(p[2 * i], p[2 * i + 1]);
    float t4a = fmaxf(t8[0], t8[1]), t4b = fmaxf(t8[2], t8[3]);
    float t4c = fmaxf(t8[4], t8[5]), t4d = fmaxf(t8[6], t8[7]);
    float mx = fmaxf(fmaxf(t4a, t4b), fmaxf(t4c, t4d));
    mx = fmaxf(mx, __shfl_xor(mx, 32, 64));

    // T13 defer-max
    if (!__all(mx <= m_run + DEFER_THR)) {
      const float mn = fmaxf(m_run, mx);
      const float corr = exp2_fast(m_run - mn);
      m_run = mn;
      l_run *= corr;
#pragma unroll
      for (int i = 0; i < 16; ++i) { acc0[i] *= corr; acc1[i] *= corr; }
    }

    float ps = 0.f;
#pragma unroll
    for (int i = 0; i < 16; ++i) {
      p[i] = exp2_fast(p[i] - m_run);
      ps += p[i];
    }
    ps += __shfl_xor(ps, 32, 64);
    l_run += ps;

    // ---- pack P, build P^T B-fragments via partner exchange ----
    unsigned W[4][2];
#pragma unroll
    for (int m = 0; m < 4; ++m)
#pragma unroll
      for (int s = 0; s < 2; ++s)
        W[m][s] = cvt_pk(p[4 * m + 2 * s], p[4 * m + 2 * s + 1]);

    FragU pf[2];
#pragma unroll
    for (int cc = 0; cc < 2; ++cc)
#pragma unroll
      for (int s = 0; s < 2; ++s) {
        const unsigned a = W[2 * cc][s];
        const unsigned b = W[2 * cc + 1][s];
        const unsigned pa = (unsigned)__shfl_xor((int)a, 32, 64);
        const unsigned pb = (unsigned)__shfl_xor((int)b, 32, 64);
        pf[cc].u[s] = hi ? pb : a;
        pf[cc].u[2 + s] = hi ? b : pa;
      }

    // ---- PV ----
    __builtin_amdgcn_s_setprio(1);
#pragma unroll
    for (int c = 0; c < 2; ++c) {
      FragU vf0, vf1;
      vf0.v = *(const bf16x8*)&vbase[(c * 2 + 0) * 512 + lane * 8];
      vf1.v = *(const bf16x8*)&vbase[(c * 2 + 1) * 512 + lane * 8];
      acc0 = __builtin_amdgcn_mfma_f32_32x32x16_bf16(vf0.v, pf[c].v, acc0, 0, 0, 0);
      acc1 = __builtin_amdgcn_mfma_f32_32x32x16_bf16(vf1.v, pf[c].v, acc1, 0, 0, 0);
    }
    __builtin_amdgcn_s_setprio(0);
  }

  // ---- split-K x4 merge ----
  if (wave & 1) {
    const int s = wave >> 1;
    float* base = &OmS[s][l31][0];
#pragma unroll
    for (int m = 0; m < 4; ++m) {
      f32x4 a, b;
#pragma unroll
      for (int e = 0; e < 4; ++e) { a[e] = acc0[4 * m + e]; b[e] = acc1[4 * m + e]; }
      *(f32x4*)(base + 8 * m + 4 * hi) = a;
      *(f32x4*)(base + 32 + 8 * m + 4 * hi) = b;
    }
    if (!hi) { mlS[s][l31][0] = m_run; mlS[s][l31][1] = l_run; }
  }
  __syncthreads();
  if (!(wave & 1)) {
    const int s = wave >> 1;
    const float m2 = mlS[s][l31][0];
    const float l2 = mlS[s][l31][1];
    const float mm = fmaxf(m_run, m2);
    const float e1 = exp2_fast(m_run - mm);
    const float e2 = exp2_fast(m2 - mm);
    m_run = mm;
    l_run = l_run * e1 + l2 * e2;
    float* base = &OmS[s][l31][0];
#pragma unroll
    for (int m = 0; m < 4; ++m) {
      f32x4 o2a = *(const f32x4*)(base + 8 * m + 4 * hi);
      f32x4 o2b = *(const f32x4*)(base + 32 + 8 * m + 4 * hi);
#pragma unroll
      for (int e = 0; e < 4; ++e) {
        acc0[4 * m + e] = acc0[4 * m + e] * e1 + o2a[e] * e2;
        acc1[4 * m + e] = acc1[4 * m + e] * e1 + o2b[e] * e2;
      }
    }
    if (wave == 2) {
#pragma unroll
      for (int m = 0; m < 4; ++m) {
        f32x4 a, b;
#pragma unroll
        for (int e = 0; e < 4; ++e) { a[e] = acc0[4 * m + e]; b[e] = acc1[4 * m + e]; }
        *(f32x4*)(base + 8 * m + 4 * hi) = a;
        *(f32x4*)(base + 32 + 8 * m + 4 * hi) = b;
      }
      if (!hi) { mlS[1][l31][0] = m_run; mlS[1][l31][1] = l_run; }
    }
  }
  __syncthreads();
  if (wave == 0) {
    const float m2 = mlS[1][l31][0];
    const float l2 = mlS[1][l31][1];
    const float mm = fmaxf(m_run, m2);
    const float e1 = exp2_fast(m_run - mm);
    const float e2 = exp2_fast(m2 - mm);
    const float inv = 1.0f / (l_run * e1 + l2 * e2);
    const float* base = &OmS[1][l31][0];
    const int qrow = qblk * 32 + l31;
#pragma unroll
    for (int m = 0; m < 4; ++m) {
      f32x4 o2a = *(const f32x4*)(base + 8 * m + 4 * hi);
      f32x4 o2b = *(const f32x4*)(base + 32 + 8 * m + 4 * hi);
      f32x4 oa, ob;
#pragma unroll
      for (int e = 0; e < 4; ++e) {
        oa[e] = (acc0[4 * m + e] * e1 + o2a[e] * e2) * inv;
        ob[e] = (acc1[4 * m + e] * e1 + o2b[e] * e2) * inv;
      }
      *(f32x4*)&Oh[(size_t)qrow * Dn + 8 * m + 4 * hi] = oa;
      *(f32x4*)&Oh[(size_t)qrow * Dn + 32 + 8 * m + 4 * hi] = ob;
    }
  }
}

extern "C" void kernel_launch(void* const* d_in, const int* in_sizes, int n_in,
                              void* d_out, int out_size, void* d_ws, size_t ws_size,
                              hipStream_t stream) {
  const float* Q = (const float*)d_in[0];
  const float* K = (const float*)d_in[1];
  const float* V = (const float*)d_in[2];
  const float* M = (const float*)d_in[3];
  float* O = (float*)d_out;

  unsigned short* Qb = (unsigned short*)d_ws;                       // 8 MB
  unsigned short* Kb = Qb + (size_t)NHEAD * FRAG_HEAD;              // 8 MB
  unsigned short* Vb = Kb + (size_t)NHEAD * FRAG_HEAD;              // 8 MB
  unsigned short* Mf = Vb + (size_t)NHEAD * FRAG_HEAD;              // 8 MB

  sdpa_prep6<<<dim3(NHEAD * 64), dim3(256), 0, stream>>>(Q, K, V, M, Qb, Kb, Vb, Mf);
  sdpa_fa6<<<dim3(NHEAD * 64), dim3(256), 0, stream>>>(Qb, Kb, Vb, Mf, O);
}